// Round 9
// baseline (397.507 us; speedup 1.0000x reference)
//
#include <hip/hip_runtime.h>
#include <hip/hip_bf16.h>
#include <stdint.h>

#define B_   8
#define ND   1024
#define D_   100
#define NV   30000
#define NC   512
#define KP   128      // K padded to 128 (100 data + zeros + C0-injection pads at 126/127)
#define NVT  472      // v-tiles padded to 8 XCD-slices of 59
#define NVP  (NVT*64) // 30208
#define VSL  59       // vt tiles per XCD slice

typedef float f32x4 __attribute__((ext_vector_type(4)));
typedef short s16x8 __attribute__((ext_vector_type(8)));
typedef short s16x4 __attribute__((ext_vector_type(4)));

#define INVD (14.0f / 1.49f)
#define C0HI 5.6875f                          // exact in bf16
#define C0LO (0.5f * INVD + 1.0f - C0HI)      // ~0.0105, bf16-rounds with ~1e-5 error

static __device__ __forceinline__ unsigned short f2bf(float x) {
    union { float f; uint32_t u; } v; v.f = x;
    uint32_t u = v.u;
    return (unsigned short)((u + 0x7FFFu + ((u >> 16) & 1u)) >> 16);  // RNE
}

// --- prep: blocks [0,1024) gather G (8 rows each, scaled by invD, pads at 126/127);
//          blocks [1024,1024+472) transpose Vv_T into Vbf with C0 pads ---
__global__ __launch_bounds__(256) void k_prep(const int* __restrict__ doc,
                                              const float* __restrict__ emb,
                                              const float* __restrict__ VvT,
                                              unsigned short* __restrict__ G,
                                              unsigned short* __restrict__ Vbf) {
    if (blockIdx.x < 1024) {
        int m = blockIdx.x * 8 + (threadIdx.x >> 5);   // 8 rows per block
        int c = threadIdx.x & 31;                      // 4-float chunk, k = 4c..4c+3
        int idx = doc[m];
        float4 e = {0.f, 0.f, 0.f, 0.f};
        if (c < 25) {
            e = *reinterpret_cast<const float4*>(&emb[(size_t)idx * D_ + c * 4]);
            e.x *= INVD; e.y *= INVD; e.z *= INVD; e.w *= INVD;
        }
        if (c == 31) { e.z = 1.f; e.w = 1.f; }         // k=126,127 -> 1.0 (C0 injection)
        s16x4 o = { (short)f2bf(e.x), (short)f2bf(e.y), (short)f2bf(e.z), (short)f2bf(e.w) };
        *reinterpret_cast<s16x4*>(&G[(size_t)m * KP + c * 4]) = o;
    } else {
        __shared__ unsigned short tile[64][136];
        int v0 = (blockIdx.x - 1024) * 64;
        int tv = threadIdx.x & 63;
        int tk0 = threadIdx.x >> 6;
        for (int k = tk0; k < KP; k += 4) {
            float val = 0.f;
            int v = v0 + tv;
            if (k < D_) { if (v < NV) val = VvT[(size_t)k * NV + v]; }
            else if (k == 126) val = C0HI;
            else if (k == 127) val = C0LO;
            tile[tv][k] = f2bf(val);
        }
        __syncthreads();
        for (int c = threadIdx.x; c < 1024; c += 256) {
            int row = c >> 4, ch = c & 15;
            *reinterpret_cast<s16x8*>(&Vbf[(size_t)(v0 + row) * KP + ch * 8]) =
                *reinterpret_cast<const s16x8*>(&tile[row][ch * 8]);
        }
    }
}

// --- main: XCD-pinned (b,vt) blocks; wave = 32 cols x 512 rows (2x2 in block);
//          A dbuf + one-iteration-deferred LDS table lookup (all stalls overlapped) ---
__global__ __launch_bounds__(256, 4) void k_main(const unsigned short* __restrict__ G,
                                                 const unsigned short* __restrict__ Vbf,
                                                 const float* __restrict__ attn,
                                                 const float* __restrict__ diff,
                                                 const float* __restrict__ start,
                                                 float* __restrict__ weighted) {
    const int xcd = blockIdx.x & 7;
    const int j   = blockIdx.x >> 3;       // 0..471
    const int b   = j / VSL;               // 0..7
    const int vt  = xcd * VSL + (j % VSL); // fixed slice per XCD
    const int v0  = vt * 64;

    const int lane = threadIdx.x & 63;
    const int wid  = threadIdx.x >> 6;
    const int ch   = wid & 1;              // col half: 32 cols
    const int rh   = wid >> 1;             // row half: 512 rows
    const int lr   = lane & 15;
    const int grp  = lane >> 4;

    // bin_w table in LDS (16 words -> banks 0-15 -> wave64 reads always conflict-free)
    __shared__ float tab[16];
    {
        float dw = diff[lr]; dw = dw > 0.f ? dw : 0.f;
#pragma unroll
        for (int off = 1; off < 16; off <<= 1) {
            float t = __shfl_up(dw, off, 16);
            if (lr >= off) dw += t;
        }
        if (threadIdx.x < 16) tab[lr] = start[0] + dw;
    }

    // B fragments (32 cols) resident in regs
    s16x8 bfr[2][4];
#pragma unroll
    for (int ct = 0; ct < 2; ++ct)
#pragma unroll
        for (int kc = 0; kc < 4; ++kc)
            bfr[ct][kc] = *reinterpret_cast<const s16x8*>(
                &Vbf[(size_t)(v0 + ch * 32 + ct * 16 + lr) * KP + grp * 8 + kc * 32]);

    __syncthreads();   // table visible to all waves

    float acc[2] = {0.f, 0.f};
    const float* attb = attn + b * ND + rh * 512 + grp * 4;
    const unsigned short* __restrict__ Gp =
        G + ((size_t)(b * ND + rh * 512 + lr)) * KP + grp * 8;

    // deferred-lookup pipeline state: w8 = in-flight table reads, atp = their attn factors
    float w8[8];
    float atp[4] = {0.f, 0.f, 0.f, 0.f};   // dummy first consume adds 0
#pragma unroll
    for (int e = 0; e < 8; ++e) w8[e] = tab[0];

    auto STEP = [&](const s16x8 af[4], int it) {
        float4 a4 = *reinterpret_cast<const float4*>(attb + it * 16);
        float cc[8];
#pragma unroll
        for (int ct = 0; ct < 2; ++ct) {
            f32x4 c = {0.f, 0.f, 0.f, 0.f};
#pragma unroll
            for (int kc = 0; kc < 4; ++kc)
                c = __builtin_amdgcn_mfma_f32_16x16x32_bf16(af[kc], bfr[ct][kc], c, 0, 0, 0);
#pragma unroll
            for (int r = 0; r < 4; ++r) cc[ct * 4 + r] = c[r];
        }
        // consume PREVIOUS iteration's lookups (lgkm latency hidden by loads+MFMAs above)
#pragma unroll
        for (int e = 0; e < 8; ++e)
            acc[e >> 2] = fmaf(atp[e & 3], w8[e], acc[e >> 2]);
        // digitize + issue THIS iteration's lookups (consumed next iter)
#pragma unroll
        for (int e = 0; e < 8; ++e) {
            float xc = fminf(fmaxf(cc[e], 0.f), 15.f);   // v_med3; trunc==floor for >=0
            w8[e] = tab[(int)xc];
        }
        atp[0] = a4.x; atp[1] = a4.y; atp[2] = a4.z; atp[3] = a4.w;
    };

    // A double-buffer over 32 iterations of 16 rows
    s16x8 afA[4], afB[4];
#pragma unroll
    for (int kc = 0; kc < 4; ++kc)
        afA[kc] = *reinterpret_cast<const s16x8*>(Gp + kc * 32);

    for (int it = 0; it < 32; it += 2) {
        const unsigned short* GpB = Gp + (size_t)(it + 1) * 16 * KP;
#pragma unroll
        for (int kc = 0; kc < 4; ++kc)
            afB[kc] = *reinterpret_cast<const s16x8*>(GpB + kc * 32);
        STEP(afA, it);
        int itn = (it + 2 < 32) ? it + 2 : 31;           // clamped harmless reload at tail
        const unsigned short* GpA = Gp + (size_t)itn * 16 * KP;
#pragma unroll
        for (int kc = 0; kc < 4; ++kc)
            afA[kc] = *reinterpret_cast<const s16x8*>(GpA + kc * 32);
        STEP(afB, it + 1);
    }
    // tail: consume final lookups
#pragma unroll
    for (int e = 0; e < 8; ++e)
        acc[e >> 2] = fmaf(atp[e & 3], w8[e], acc[e >> 2]);

    // reduce: grp-groups within wave, then the two row-halves via LDS
    __shared__ float red[2][64];
#pragma unroll
    for (int ct = 0; ct < 2; ++ct) {
        float a = acc[ct];
        a += __shfl_xor(a, 16, 64);
        a += __shfl_xor(a, 32, 64);
        if (lane < 16) red[rh][ch * 32 + ct * 16 + lane] = a;
    }
    __syncthreads();
    if (threadIdx.x < 64) {
        weighted[(size_t)b * NVP + v0 + threadIdx.x] =
            red[0][threadIdx.x] + red[1][threadIdx.x];
    }
}

// --- final: out[b,n] = <weighted[b,:], phi[n,:]> / max(L1(phi[n,:]),1e-12) ; 2 rows/block ---
__global__ __launch_bounds__(512) void k_final(const float* __restrict__ phi,
                                               const float* __restrict__ weighted,
                                               float* __restrict__ out) {
    const int n0 = blockIdx.x * 2;
    const int t = threadIdx.x;       // 512 threads = 8 waves
    float s1[2] = {0.f, 0.f};
    float dot[2][8];
#pragma unroll
    for (int nn = 0; nn < 2; ++nn)
#pragma unroll
        for (int b = 0; b < 8; ++b) dot[nn][b] = 0.f;

    for (int v4 = t; v4 < NV / 4; v4 += 512) {
        float4 w4[8];
#pragma unroll
        for (int b = 0; b < 8; ++b)
            w4[b] = *reinterpret_cast<const float4*>(&weighted[(size_t)b * NVP + v4 * 4]);
#pragma unroll
        for (int nn = 0; nn < 2; ++nn) {
            float4 p = *reinterpret_cast<const float4*>(&phi[(size_t)(n0 + nn) * NV + v4 * 4]);
            s1[nn] += fabsf(p.x) + fabsf(p.y) + fabsf(p.z) + fabsf(p.w);
#pragma unroll
            for (int b = 0; b < 8; ++b)
                dot[nn][b] += p.x * w4[b].x + p.y * w4[b].y + p.z * w4[b].z + p.w * w4[b].w;
        }
    }

    float vals[18];
#pragma unroll
    for (int nn = 0; nn < 2; ++nn) vals[nn] = s1[nn];
#pragma unroll
    for (int nn = 0; nn < 2; ++nn)
#pragma unroll
        for (int b = 0; b < 8; ++b) vals[2 + nn * 8 + b] = dot[nn][b];

    __shared__ float red[8][18];
    __shared__ float sums[18];
    const int lane = t & 63, wvv = t >> 6;
#pragma unroll
    for (int i = 0; i < 18; ++i) {
        float x = vals[i];
        x += __shfl_down(x, 32, 64);
        x += __shfl_down(x, 16, 64);
        x += __shfl_down(x, 8, 64);
        x += __shfl_down(x, 4, 64);
        x += __shfl_down(x, 2, 64);
        x += __shfl_down(x, 1, 64);
        if (lane == 0) red[wvv][i] = x;
    }
    __syncthreads();
    if (t < 18) {
        float s = 0.f;
        for (int w = 0; w < 8; ++w) s += red[w][t];
        sums[t] = s;
    }
    __syncthreads();
    if (t < 16) {
        int nn = t >> 3, b = t & 7;
        float denom = sums[nn]; if (denom < 1e-12f) denom = 1e-12f;
        out[b * NC + n0 + nn] = sums[2 + t] / denom;
    }
}

extern "C" void kernel_launch(void* const* d_in, const int* in_sizes, int n_in,
                              void* d_out, int out_size, void* d_ws, size_t ws_size,
                              hipStream_t stream) {
    const int*   doc   = (const int*)d_in[0];
    const float* attn  = (const float*)d_in[1];
    const float* emb   = (const float*)d_in[2];
    const float* VvT   = (const float*)d_in[3];
    const float* phi   = (const float*)d_in[4];
    const float* diff  = (const float*)d_in[5];
    const float* start = (const float*)d_in[6];

    char* ws = (char*)d_ws;
    unsigned short* Vbf = (unsigned short*)ws;                 // 30208*128*2 = 7,733,248 B
    unsigned short* G   = (unsigned short*)(ws + 7733248);     // 8192*128*2  = 2,097,152 B
    float* weighted     = (float*)(ws + 7733248 + 2097152);    // 8*30208*4   =   966,656 B
    float* out          = (float*)d_out;

    k_prep  <<<1024 + NVT, 256, 0, stream>>>(doc, emb, VvT, G, Vbf);
    k_main  <<<B_ * NVT, 256, 0, stream>>>(G, Vbf, attn, diff, start, weighted);
    k_final <<<NC / 2, 512, 0, stream>>>(phi, weighted, out);
}

// Round 10
// 228.676 us; speedup vs baseline: 1.7383x; 1.7383x over previous
//
#include <hip/hip_runtime.h>
#include <hip/hip_bf16.h>
#include <stdint.h>

#define B_   8
#define ND   1024
#define D_   100
#define NV   30000
#define NC   512
#define KP   128        // K padded to 128 (100 data + zeros + C0-injection pads at 126/127)
#define NVT  480        // 64-col v-tiles, padded: 120 groups of 256 cols = 8 XCDs x 15
#define NVP  (NVT*64)   // 30720
#define NG   120        // 256-col groups
#define GPX  15         // groups per XCD slice

typedef float f32x4 __attribute__((ext_vector_type(4)));
typedef short s16x8 __attribute__((ext_vector_type(8)));
typedef short s16x4 __attribute__((ext_vector_type(4)));

#define INVD (14.0f / 1.49f)
#define C0HI 5.6875f                          // exact in bf16
#define C0LO (0.5f * INVD + 1.0f - C0HI)      // ~0.0105

#define AS1 __attribute__((address_space(1)))
#define AS3 __attribute__((address_space(3)))

static __device__ __forceinline__ void gload16(const void* g, void* l) {
    __builtin_amdgcn_global_load_lds((const AS1 uint32_t*)g, (AS3 uint32_t*)l, 16, 0, 0);
}

static __device__ __forceinline__ unsigned short f2bf(float x) {
    union { float f; uint32_t u; } v; v.f = x;
    uint32_t u = v.u;
    return (unsigned short)((u + 0x7FFFu + ((u >> 16) & 1u)) >> 16);  // RNE
}

// --- prep: blocks [0,1024) gather G rows (scaled by invD, C0 pads at k=126/127),
//          stored with 16B-chunk XOR swizzle: chunk ^= (row & 15)  [bank-conflict-free
//          LDS reads in k_main; staging stays linear on both sides].
//          blocks [1024,1024+480) transpose Vv_T into Vbf (unswizzled) with C0 pads ---
__global__ __launch_bounds__(256) void k_prep(const int* __restrict__ doc,
                                              const float* __restrict__ emb,
                                              const float* __restrict__ VvT,
                                              unsigned short* __restrict__ G,
                                              unsigned short* __restrict__ Vbf) {
    if (blockIdx.x < 1024) {
        int m = blockIdx.x * 8 + (threadIdx.x >> 5);   // row 0..8191
        int c = threadIdx.x & 31;                      // 4-short group, k = 4c..4c+3
        int idx = doc[m];
        float4 e = {0.f, 0.f, 0.f, 0.f};
        if (c < 25) {
            e = *reinterpret_cast<const float4*>(&emb[(size_t)idx * D_ + c * 4]);
            e.x *= INVD; e.y *= INVD; e.z *= INVD; e.w *= INVD;
        }
        if (c == 31) { e.z = 1.f; e.w = 1.f; }         // k=126,127 -> 1.0 (C0 injection)
        s16x4 o = { (short)f2bf(e.x), (short)f2bf(e.y), (short)f2bf(e.z), (short)f2bf(e.w) };
        int chunk = c >> 1, half = c & 1;
        int sw = chunk ^ (m & 15);                     // XOR swizzle within row
        *reinterpret_cast<s16x4*>(&G[(size_t)m * KP + sw * 8 + half * 4]) = o;
    } else {
        __shared__ unsigned short tile[64][136];
        int v0 = (blockIdx.x - 1024) * 64;
        int tv = threadIdx.x & 63;
        int tk0 = threadIdx.x >> 6;
        for (int k = tk0; k < KP; k += 4) {
            float val = 0.f;
            int v = v0 + tv;
            if (k < D_) { if (v < NV) val = VvT[(size_t)k * NV + v]; }
            else if (k == 126) val = C0HI;
            else if (k == 127) val = C0LO;
            tile[tv][k] = f2bf(val);
        }
        __syncthreads();
        for (int c = threadIdx.x; c < 1024; c += 256) {
            int row = c >> 4, ch = c & 15;
            *reinterpret_cast<s16x8*>(&Vbf[(size_t)(v0 + row) * KP + ch * 8]) =
                *reinterpret_cast<const s16x8*>(&tile[row][ch * 8]);
        }
    }
}

// --- main: block = 256 cols x 1024 rows; A staged to LDS once (global_load_lds,
//          double-buffered), 3.2x less L2 traffic than per-wave direct loads.
//          Each wave owns 64 cols; digit=clamp(trunc(c),0,15); LDS tab lookup. ---
__global__ __launch_bounds__(256, 2) void k_main(const unsigned short* __restrict__ G,
                                                 const unsigned short* __restrict__ Vbf,
                                                 const float* __restrict__ attn,
                                                 const float* __restrict__ diff,
                                                 const float* __restrict__ start,
                                                 float* __restrict__ weighted) {
    const int xcd = blockIdx.x & 7;
    const int j   = blockIdx.x >> 3;        // 0..119
    const int b   = j / GPX;                // 0..7 (b-major within XCD slice)
    const int g   = j % GPX;
    const int v0  = (xcd * GPX + g) * 256;  // fixed 256-col group per XCD slice

    const int tid  = threadIdx.x;
    const int lane = tid & 63;
    const int wid  = tid >> 6;              // col quarter (64 cols)
    const int lr   = lane & 15;
    const int grp  = lane >> 4;

    __shared__ unsigned short abuf[2][64 * KP];   // 2 x 16 KB A-tile
    __shared__ float tab[16];
    __shared__ float red[4][64];

    // bin_w table via relu + 16-lane inclusive scan
    {
        float dw = diff[lr]; dw = dw > 0.f ? dw : 0.f;
#pragma unroll
        for (int off = 1; off < 16; off <<= 1) {
            float t = __shfl_up(dw, off, 16);
            if (lr >= off) dw += t;
        }
        if (tid < 16) tab[lr] = start[0] + dw;
    }

    // B fragments: wave's 64 cols resident in regs
    s16x8 bfr[4][4];
#pragma unroll
    for (int ct = 0; ct < 4; ++ct)
#pragma unroll
        for (int kc = 0; kc < 4; ++kc)
            bfr[ct][kc] = *reinterpret_cast<const s16x8*>(
                &Vbf[(size_t)(v0 + wid * 64 + ct * 16 + lr) * KP + grp * 8 + kc * 32]);

    // swizzled LDS read offsets (row lr, chunk (grp+kc*4)^lr), loop-invariant
    int roff[4];
#pragma unroll
    for (int kc = 0; kc < 4; ++kc)
        roff[kc] = lr * 256 + (((grp + kc * 4) ^ lr) << 4);

    const char* Gb = (const char*)G + (size_t)b * ND * 256;  // b's rows (swizzled storage)
    const float* attb = attn + b * ND + grp * 4;

    auto STAGE = [&](int buf, int d0) {
#pragma unroll
        for (int q = 0; q < 4; ++q) {
            const void* src = Gb + (size_t)d0 * 256 + q * 4096 + wid * 1024 + lane * 16;
            void* dst = (char*)&abuf[buf][0] + q * 4096 + wid * 1024;  // wave-uniform
            gload16(src, dst);
        }
    };

    float acc[4] = {0.f, 0.f, 0.f, 0.f};

    STAGE(0, 0);
    __syncthreads();                      // barrier drains vmcnt -> buf0 ready
    int cur = 0;
    for (int s = 0; s < 16; ++s) {
        if (s + 1 < 16) STAGE(cur ^ 1, (s + 1) * 64);   // prefetch next tile
        const char* ab = (const char*)&abuf[cur][0];
#pragma unroll
        for (int it2 = 0; it2 < 4; ++it2) {
            s16x8 af[4];
#pragma unroll
            for (int kc = 0; kc < 4; ++kc)
                af[kc] = *reinterpret_cast<const s16x8*>(ab + it2 * 4096 + roff[kc]);
            float4 a4 = *reinterpret_cast<const float4*>(attb + s * 64 + it2 * 16);
            float at[4] = {a4.x, a4.y, a4.z, a4.w};
            float cc[16];
#pragma unroll
            for (int ct = 0; ct < 4; ++ct) {
                f32x4 c = {0.f, 0.f, 0.f, 0.f};
#pragma unroll
                for (int kc = 0; kc < 4; ++kc)
                    c = __builtin_amdgcn_mfma_f32_16x16x32_bf16(af[kc], bfr[ct][kc], c, 0, 0, 0);
#pragma unroll
                for (int r = 0; r < 4; ++r) cc[ct * 4 + r] = c[r];
            }
#pragma unroll
            for (int e = 0; e < 16; ++e) {
                float xc = fminf(fmaxf(cc[e], 0.f), 15.f);   // v_med3; trunc==floor >=0
                acc[e >> 2] = fmaf(at[e & 3], tab[(int)xc], acc[e >> 2]);
            }
        }
        __syncthreads();                  // next tile staged AND cur fully consumed
        cur ^= 1;
    }

    // wave owns distinct 64 cols: reduce over grp groups, store via LDS coalesced
#pragma unroll
    for (int ct = 0; ct < 4; ++ct) {
        float a = acc[ct];
        a += __shfl_xor(a, 16, 64);
        a += __shfl_xor(a, 32, 64);
        if (lane < 16) red[wid][ct * 16 + lr] = a;
    }
    __syncthreads();
    weighted[(size_t)b * NVP + v0 + tid] = red[tid >> 6][tid & 63];
}

// --- final: out[b,n] = <weighted[b,:], phi[n,:]> / max(L1(phi[n,:]),1e-12) ; 2 rows/block ---
__global__ __launch_bounds__(512) void k_final(const float* __restrict__ phi,
                                               const float* __restrict__ weighted,
                                               float* __restrict__ out) {
    const int n0 = blockIdx.x * 2;
    const int t = threadIdx.x;       // 512 threads = 8 waves
    float s1[2] = {0.f, 0.f};
    float dot[2][8];
#pragma unroll
    for (int nn = 0; nn < 2; ++nn)
#pragma unroll
        for (int b = 0; b < 8; ++b) dot[nn][b] = 0.f;

    for (int v4 = t; v4 < NV / 4; v4 += 512) {
        float4 w4[8];
#pragma unroll
        for (int b = 0; b < 8; ++b)
            w4[b] = *reinterpret_cast<const float4*>(&weighted[(size_t)b * NVP + v4 * 4]);
#pragma unroll
        for (int nn = 0; nn < 2; ++nn) {
            float4 p = *reinterpret_cast<const float4*>(&phi[(size_t)(n0 + nn) * NV + v4 * 4]);
            s1[nn] += fabsf(p.x) + fabsf(p.y) + fabsf(p.z) + fabsf(p.w);
#pragma unroll
            for (int b = 0; b < 8; ++b)
                dot[nn][b] += p.x * w4[b].x + p.y * w4[b].y + p.z * w4[b].z + p.w * w4[b].w;
        }
    }

    float vals[18];
#pragma unroll
    for (int nn = 0; nn < 2; ++nn) vals[nn] = s1[nn];
#pragma unroll
    for (int nn = 0; nn < 2; ++nn)
#pragma unroll
        for (int b = 0; b < 8; ++b) vals[2 + nn * 8 + b] = dot[nn][b];

    __shared__ float red[8][18];
    __shared__ float sums[18];
    const int lane = t & 63, wvv = t >> 6;
#pragma unroll
    for (int i = 0; i < 18; ++i) {
        float x = vals[i];
        x += __shfl_down(x, 32, 64);
        x += __shfl_down(x, 16, 64);
        x += __shfl_down(x, 8, 64);
        x += __shfl_down(x, 4, 64);
        x += __shfl_down(x, 2, 64);
        x += __shfl_down(x, 1, 64);
        if (lane == 0) red[wvv][i] = x;
    }
    __syncthreads();
    if (t < 18) {
        float s = 0.f;
        for (int w = 0; w < 8; ++w) s += red[w][t];
        sums[t] = s;
    }
    __syncthreads();
    if (t < 16) {
        int nn = t >> 3, b = t & 7;
        float denom = sums[nn]; if (denom < 1e-12f) denom = 1e-12f;
        out[b * NC + n0 + nn] = sums[2 + t] / denom;
    }
}

extern "C" void kernel_launch(void* const* d_in, const int* in_sizes, int n_in,
                              void* d_out, int out_size, void* d_ws, size_t ws_size,
                              hipStream_t stream) {
    const int*   doc   = (const int*)d_in[0];
    const float* attn  = (const float*)d_in[1];
    const float* emb   = (const float*)d_in[2];
    const float* VvT   = (const float*)d_in[3];
    const float* phi   = (const float*)d_in[4];
    const float* diff  = (const float*)d_in[5];
    const float* start = (const float*)d_in[6];

    char* ws = (char*)d_ws;
    unsigned short* Vbf = (unsigned short*)ws;                 // 30720*128*2 = 7,864,320 B
    unsigned short* G   = (unsigned short*)(ws + 7864320);     // 8192*128*2  = 2,097,152 B
    float* weighted     = (float*)(ws + 7864320 + 2097152);    // 8*30720*4   =   983,040 B
    float* out          = (float*)d_out;

    k_prep  <<<1024 + NVT, 256, 0, stream>>>(doc, emb, VvT, G, Vbf);
    k_main  <<<B_ * NG, 256, 0, stream>>>(G, Vbf, attn, diff, start, weighted);
    k_final <<<NC / 2, 512, 0, stream>>>(phi, weighted, out);
}